// Round 5
// baseline (1779.417 us; speedup 1.0000x reference)
//
#include <hip/hip_runtime.h>

// Round 5: small-tile / many-wave gather-conv.
// ROWS=16 per block, KSPLIT waves each owning TPW taps (weights zero-padded
// to KPAD), direct per-lane fragment gathers (no per-tap barriers, no LDS
// staging), one LDS reduce + barrier at the end. Round-4 launch fusions kept.

typedef _Float16 f16;
typedef _Float16 f16x8 __attribute__((ext_vector_type(8)));
typedef float    f32x4 __attribute__((ext_vector_type(4)));

#define BN_EPS_F 1e-3f

// ---------------------------------------------------------------------------
__global__ __launch_bounds__(256)
void fill_zero(float4* __restrict__ p, long n4)
{
    long i  = blockIdx.x * 256L + threadIdx.x;
    long st = (long)gridDim.x * 256L;
    float4 z = make_float4(0.f, 0.f, 0.f, 0.f);
    for (; i < n4; i += st) p[i] = z;
}

// input cast: vf f32 [3*M0][16] -> vf16 f16 [3*M0][32] (hi 16 ch zero)
__global__ __launch_bounds__(256)
void vf_convert(const float* __restrict__ vf, f16* __restrict__ vf16, int nrows)
{
    int i = blockIdx.x * 256 + threadIdx.x;
    if (i >= nrows * 32) return;
    int r = i >> 5, c = i & 31;
    vf16[i] = (c < 16) ? (f16)vf[r * 16 + c] : (f16)0;
}

// weight transforms: w [K][Ci][Co] f32 -> wT [KPAD][Co][CiD] f16 (zero pad)
struct WXA { const float* s; f16* d; int K, Kp, Ci, Co, CiD, off; };
struct WXAll { WXA w[11]; };

__global__ __launch_bounds__(256)
void wxform_all(WXAll wa, int total)
{
    int i = blockIdx.x * 256 + threadIdx.x;
    if (i >= total) return;
    int j = 0;
    #pragma unroll
    for (int t = 1; t < 11; ++t) if (i >= wa.w[t].off) j = t;
    const float* s = wa.w[j].s;
    f16* d = wa.w[j].d;
    int K = wa.w[j].K, Ci = wa.w[j].Ci, Co = wa.w[j].Co, CiD = wa.w[j].CiD;
    int e = i - wa.w[j].off;
    int cc = Co * CiD;
    int k = e / cc; int rem = e - k * cc;
    int co = rem / CiD; int ci = rem - co * CiD;
    float v = (k < K && ci < Ci) ? s[((size_t)k * Ci + ci) * Co + co] : 0.f;
    d[e] = (f16)v;
}

// ---------------------------------------------------------------------------
// gather-conv: 16 output rows/block, KSPLIT=KPAD/TPW waves, wave g owns taps
// [g*TPW, g*TPW+TPW). Direct per-lane global loads of MFMA fragments.
// Fragment layout (verified r2): A/B lane l: row/col=l&15, k-contig 8 at
// (l>>4)*8; C/D: col=lane&15, row=(lane>>4)*4+reg.
// ---------------------------------------------------------------------------
template<int Ci, int Co, int K, int KPAD, int TPW, bool SCATTER>
__global__ __launch_bounds__((KPAD/TPW)*64)
void gconv(const f16* __restrict__ fin, const int* __restrict__ idx,
           const f16* __restrict__ wT,    // [KPAD][Co][Ci]
           const float* __restrict__ bnp, // [4][Co]
           const float* __restrict__ avec,
           f16* __restrict__ fout,
           const int* __restrict__ coords, float* __restrict__ dout,
           int M, int blocksPerFrame, long finStride, long foutStride)
{
    constexpr int KSPLIT = KPAD / TPW;
    constexpr int NF  = Co / 16;
    constexpr int KK  = Ci / 32;
    constexpr int CoP = Co + 4;

    __shared__ float red[KSPLIT - 1][16][CoP];

    const int tid  = threadIdx.x;
    const int lane = tid & 63;
    const int g    = tid >> 6;          // wave id = tap group
    const int l15  = lane & 15;
    const int kg   = lane >> 4;

    const int bid   = blockIdx.x;
    const int frame = bid / blocksPerFrame;
    const int fb    = bid - frame * blocksPerFrame;
    const f16* finF = fin + (long)frame * finStride;
    f16* foutF      = fout + (long)frame * foutStride;
    const int m0    = fb * 16;
    const int mrow  = m0 + l15;
    const bool rowok = mrow < M;

    // per-lane idx loads for this wave's taps
    const int k0 = g * TPW;
    int nidx[TPW];
    #pragma unroll
    for (int kt = 0; kt < TPW; ++kt) {
        int k = k0 + kt;
        nidx[kt] = (rowok && k < K) ? idx[(long)mrow * K + k] : -1;
    }

    f32x4 acc[NF];
    #pragma unroll
    for (int nf = 0; nf < NF; ++nf) acc[nf] = (f32x4){0.f, 0.f, 0.f, 0.f};

    #pragma unroll
    for (int kt = 0; kt < TPW; ++kt) {
        int k = k0 + kt;
        int n = nidx[kt];
        #pragma unroll
        for (int kk = 0; kk < KK; ++kk) {
            f16x8 af = {};
            if (n >= 0)
                af = *(const f16x8*)&finF[(long)n * Ci + kk * 32 + kg * 8];
            #pragma unroll
            for (int nf = 0; nf < NF; ++nf) {
                f16x8 bf = *(const f16x8*)&wT[((long)k * Co + nf * 16 + l15) * Ci + kk * 32 + kg * 8];
                acc[nf] = __builtin_amdgcn_mfma_f32_16x16x32_f16(af, bf, acc[nf], 0, 0, 0);
            }
        }
    }

    // cross-wave reduce: waves g>0 dump, wave 0 accumulates + epilogue
    if (g > 0) {
        #pragma unroll
        for (int nf = 0; nf < NF; ++nf)
            #pragma unroll
            for (int j = 0; j < 4; ++j)
                red[g - 1][kg * 4 + j][nf * 16 + l15] = acc[nf][j];
    }
    __syncthreads();
    if (g == 0) {
        #pragma unroll
        for (int nf = 0; nf < NF; ++nf) {
            int c = nf * 16 + l15;
            float gg = bnp[c], bb = bnp[Co + c], mu = bnp[2 * Co + c], vv = bnp[3 * Co + c];
            float sc = gg * rsqrtf(vv + BN_EPS_F);
            float sh = bb - mu * sc;
            float av = avec ? avec[c] : 0.f;
            #pragma unroll
            for (int j = 0; j < 4; ++j) {
                int row = kg * 4 + j;
                int m = m0 + row;
                if (m < M) {
                    float x = acc[nf][j] + av;
                    #pragma unroll
                    for (int gi = 0; gi < KSPLIT - 1; ++gi)
                        x += red[gi][row][c];
                    float y = fmaxf(fmaf(x, sc, sh), 0.f);
                    foutF[(long)m * Co + c] = (f16)y;
                    if (SCATTER) {
                        int z  = coords[m * 3 + 0];
                        int yy = coords[m * 3 + 1];
                        int xx = coords[m * 3 + 2];
                        dout[(long)(c * 4 + z) * (320 * 320) + yy * 320 + xx] = y;
                    }
                }
            }
        }
    }
}

// ---------------------------------------------------------------------------
// adapt: per-block partial of sum_rows relu(bn_ad(s @ w_ad1)) for all 3 levels
// ---------------------------------------------------------------------------
__global__ __launch_bounds__(64)
void adapt_partial3(const f16* __restrict__ x3, const f16* __restrict__ x7,
                    const f16* __restrict__ x11,
                    const float* __restrict__ w_ad1, const float* __restrict__ bn_ad,
                    float* __restrict__ pb,
                    int M1, int M2, int M3, int g1, int g2)
{
    __shared__ float wl[64 * 64];
    const int c = threadIdx.x;
    for (int i = c; i < 64 * 64; i += 64) wl[i] = w_ad1[i];
    float gg = bn_ad[c], bb = bn_ad[64 + c], mu = bn_ad[128 + c], vv = bn_ad[192 + c];
    float sc = gg * rsqrtf(vv + BN_EPS_F);
    float sh = bb - mu * sc;
    __syncthreads();

    int b = blockIdx.x;
    const f16* s; int M, r0;
    if (b < g1)           { s = x3;  M = M1; r0 = b * 64; }
    else if (b < g1 + g2) { s = x7;  M = M2; r0 = (b - g1) * 64; }
    else                  { s = x11; M = M3; r0 = (b - g1 - g2) * 64; }

    float hacc = 0.f;
    int r1 = min(r0 + 64, M);
    for (int r = r0; r < r1; ++r) {
        float acc = 0.f;
        #pragma unroll
        for (int i8 = 0; i8 < 8; ++i8) {
            f16x8 sv = *(const f16x8*)&s[(size_t)r * 64 + i8 * 8];
            #pragma unroll
            for (int e = 0; e < 8; ++e)
                acc = fmaf((float)sv[e], wl[(i8 * 8 + e) * 64 + c], acc);
        }
        hacc += fmaxf(fmaf(acc, sc, sh), 0.f);
    }
    pb[(size_t)b * 64 + c] = hacc;
}

__global__ __launch_bounds__(192)
void adapt_final3(const float* __restrict__ pb, const float* __restrict__ w_ad2,
                  float* __restrict__ av, int g1, int g2, int g3,
                  float invM1, float invM2, float invM3)
{
    __shared__ float h[3][64];
    const int lvl = threadIdx.x >> 6;
    const int c   = threadIdx.x & 63;
    int base = (lvl == 0) ? 0 : (lvl == 1 ? g1 : g1 + g2);
    int n    = (lvl == 0) ? g1 : (lvl == 1 ? g2 : g3);
    float invM = (lvl == 0) ? invM1 : (lvl == 1 ? invM2 : invM3);
    float acc = 0.f;
    for (int i = 0; i < n; ++i) acc += pb[(size_t)(base + i) * 64 + c];
    h[lvl][c] = acc * invM;
    __syncthreads();
    float o = 0.f;
    #pragma unroll 8
    for (int j = 0; j < 64; ++j) o = fmaf(h[lvl][j], w_ad2[j * 64 + c], o);
    av[lvl * 64 + c] = o * 0.1f;
}

// ---------------------------------------------------------------------------
extern "C" void kernel_launch(void* const* d_in, const int* in_sizes, int n_in,
                              void* d_out, int out_size, void* d_ws, size_t ws_size,
                              hipStream_t stream)
{
    const float* vf      = (const float*)d_in[0];
    const float* w_subm1 = (const float*)d_in[1];
    const float* w_subm2 = (const float*)d_in[2];
    const float* w_spcv1 = (const float*)d_in[3];
    const float* w_subm3 = (const float*)d_in[4];
    const float* w_subm4 = (const float*)d_in[5];
    const float* w_subm5 = (const float*)d_in[6];
    const float* w_spcv2 = (const float*)d_in[7];
    const float* w_subm6 = (const float*)d_in[8];
    const float* w_subm7 = (const float*)d_in[9];
    const float* w_subm8 = (const float*)d_in[10];
    const float* w_spcv3 = (const float*)d_in[11];
    const float* w_ad1   = (const float*)d_in[12];
    const float* w_ad2   = (const float*)d_in[13];
    const float* bn32    = (const float*)d_in[14];
    const float* bn64    = (const float*)d_in[15];
    const float* bn_ad   = (const float*)d_in[16];
    const int* nbr0    = (const int*)d_in[17];
    const int* idx1    = (const int*)d_in[18];
    const int* nbr1    = (const int*)d_in[19];
    const int* idx2    = (const int*)d_in[20];
    const int* nbr2    = (const int*)d_in[21];
    const int* idx3    = (const int*)d_in[22];
    const int* coords3 = (const int*)d_in[23];

    const int M0 = in_sizes[0]  / (3 * 16);
    const int M1 = in_sizes[18] / 27;
    const int M2 = in_sizes[20] / 27;
    const int M3 = in_sizes[22] / 3;

    char* base = (char*)d_ws;
    size_t off = 0;
    auto alloc = [&](size_t bytes) -> void* {
        void* p = base + off;
        off = (off + bytes + 255) & ~(size_t)255;
        return p;
    };
    // weights [KPAD][Co][CiD] f16
    f16* wt1  = (f16*)alloc((size_t)28 * 32 * 32 * 2);
    f16* wt2  = (f16*)alloc((size_t)28 * 32 * 32 * 2);
    f16* wtc1 = (f16*)alloc((size_t)28 * 64 * 32 * 2);
    f16* wt3  = (f16*)alloc((size_t)28 * 64 * 64 * 2);
    f16* wt4  = (f16*)alloc((size_t)28 * 64 * 64 * 2);
    f16* wt5  = (f16*)alloc((size_t)28 * 64 * 64 * 2);
    f16* wtc2 = (f16*)alloc((size_t)28 * 64 * 64 * 2);
    f16* wt6  = (f16*)alloc((size_t)28 * 64 * 64 * 2);
    f16* wt7  = (f16*)alloc((size_t)28 * 64 * 64 * 2);
    f16* wt8  = (f16*)alloc((size_t)28 * 64 * 64 * 2);
    f16* wtc3 = (f16*)alloc((size_t)4  * 64 * 64 * 2);
    // features
    f16* vf16  = (f16*)alloc((size_t)3 * M0 * 32 * 2);
    f16* buf0a = (f16*)alloc((size_t)3 * M0 * 32 * 2);
    f16* buf0b = (f16*)alloc((size_t)3 * M0 * 32 * 2);
    f16* x3    = (f16*)alloc((size_t)M1 * 64 * 2);
    f16* buf1a = (f16*)alloc((size_t)M1 * 64 * 2);
    f16* buf1b = (f16*)alloc((size_t)M1 * 64 * 2);
    f16* x7    = (f16*)alloc((size_t)M2 * 64 * 2);
    f16* buf2a = (f16*)alloc((size_t)M2 * 64 * 2);
    f16* buf2b = (f16*)alloc((size_t)M2 * 64 * 2);
    f16* x11   = (f16*)alloc((size_t)M3 * 64 * 2);
    float* av  = (float*)alloc(192 * 4);
    const int g1a = (M1 + 63) / 64, g2a = (M2 + 63) / 64, g3a = (M3 + 63) / 64;
    float* pb  = (float*)alloc((size_t)(g1a + g2a + g3a) * 64 * 4);
    (void)ws_size; (void)n_in;

    // --- setup: weight transforms (1 launch), input cast (1), output zero (1)
    WXAll wa;
    int woff = 0;
    auto addw = [&](int slot, const float* s, f16* d, int K, int Kp, int Ci, int Co, int CiD) {
        wa.w[slot] = {s, d, K, Kp, Ci, Co, CiD, woff};
        woff += Kp * Co * CiD;
    };
    addw(0,  w_subm1, wt1,  27, 28, 16, 32, 32);
    addw(1,  w_subm2, wt2,  27, 28, 32, 32, 32);
    addw(2,  w_spcv1, wtc1, 27, 28, 32, 64, 32);
    addw(3,  w_subm3, wt3,  27, 28, 64, 64, 64);
    addw(4,  w_subm4, wt4,  27, 28, 64, 64, 64);
    addw(5,  w_subm5, wt5,  27, 28, 64, 64, 64);
    addw(6,  w_spcv2, wtc2, 27, 28, 64, 64, 64);
    addw(7,  w_subm6, wt6,  27, 28, 64, 64, 64);
    addw(8,  w_subm7, wt7,  27, 28, 64, 64, 64);
    addw(9,  w_subm8, wt8,  27, 28, 64, 64, 64);
    addw(10, w_spcv3, wtc3, 3,  4,  64, 64, 64);
    wxform_all<<<(woff + 255) / 256, 256, 0, stream>>>(wa, woff);
    vf_convert<<<(3 * M0 * 32 + 255) / 256, 256, 0, stream>>>(vf, vf16, 3 * M0);
    fill_zero<<<2048, 256, 0, stream>>>((float4*)d_out, (long)out_size / 4);

    const int g0w = (M0 + 15) / 16;
    const int g1w = (M1 + 15) / 16;
    const int g2w = (M2 + 15) / 16;
    const int g3w = (M3 + 15) / 16;
    const long s0 = (long)M0 * 32;

    // batched over all 3 frames (independent of temporal state)
    gconv<32,32,27,28,4,false><<<3 * g0w, 448, 0, stream>>>(
        vf16,  nbr0, wt1, bn32,       nullptr, buf0a, nullptr, nullptr, M0, g0w, s0, s0);
    gconv<32,32,27,28,4,false><<<3 * g0w, 448, 0, stream>>>(
        buf0a, nbr0, wt2, bn32 + 128, nullptr, buf0b, nullptr, nullptr, M0, g0w, s0, s0);

    for (int t = 0; t < 3; ++t) {
        const float* a0 = (t == 0) ? nullptr : av + 0;
        const float* a1 = (t == 0) ? nullptr : av + 64;
        const float* a2 = (t == 0) ? nullptr : av + 128;
        float* doutT = (float*)d_out + (size_t)t * 256 * 320 * 320;

        gconv<32,64,27,28,4,false><<<g1w, 448, 0, stream>>>(
            buf0b + (long)t * s0, idx1, wtc1, bn64, a0, x3, nullptr, nullptr, M1, g1w, 0, 0);
        gconv<64,64,27,28,4,false><<<g1w, 448, 0, stream>>>(
            x3,    nbr1, wt3, bn64 + 256,  nullptr, buf1a, nullptr, nullptr, M1, g1w, 0, 0);
        gconv<64,64,27,28,4,false><<<g1w, 448, 0, stream>>>(
            buf1a, nbr1, wt4, bn64 + 512,  nullptr, buf1b, nullptr, nullptr, M1, g1w, 0, 0);
        gconv<64,64,27,28,4,false><<<g1w, 448, 0, stream>>>(
            buf1b, nbr1, wt5, bn64 + 768,  nullptr, buf1a, nullptr, nullptr, M1, g1w, 0, 0);
        gconv<64,64,27,28,4,false><<<g2w, 448, 0, stream>>>(
            buf1a, idx2, wtc2, bn64 + 1024, a1,     x7,    nullptr, nullptr, M2, g2w, 0, 0);
        gconv<64,64,27,28,4,false><<<g2w, 448, 0, stream>>>(
            x7,    nbr2, wt6, bn64 + 1280, nullptr, buf2a, nullptr, nullptr, M2, g2w, 0, 0);
        gconv<64,64,27,28,4,false><<<g2w, 448, 0, stream>>>(
            buf2a, nbr2, wt7, bn64 + 1536, nullptr, buf2b, nullptr, nullptr, M2, g2w, 0, 0);
        gconv<64,64,27,28,4,false><<<g2w, 448, 0, stream>>>(
            buf2b, nbr2, wt8, bn64 + 1792, nullptr, buf2a, nullptr, nullptr, M2, g2w, 0, 0);
        gconv<64,64,3,4,1,true><<<g3w, 256, 0, stream>>>(
            buf2a, idx3, wtc3, bn64 + 2048, a2,    x11,   coords3, doutT,   M3, g3w, 0, 0);

        if (t < 2) {
            adapt_partial3<<<g1a + g2a + g3a, 64, 0, stream>>>(
                x3, x7, x11, w_ad1, bn_ad, pb, M1, M2, M3, g1a, g2a);
            adapt_final3<<<1, 192, 0, stream>>>(
                pb, w_ad2, av, g1a, g2a, g3a, 1.f / M1, 1.f / M2, 1.f / M3);
        }
    }
}

// Round 6
// 1531.648 us; speedup vs baseline: 1.1618x; 1.1618x over previous
//
#include <hip/hip_runtime.h>

// Round 6: weight-amortized, single-barrier-per-tap gather-conv.
// 64 rows/block, 4 waves, each wave owns 16 complete rows (no k-split, no
// cross-wave reduce). Weights double-buffered in LDS (one barrier per tap);
// A-fragments gathered direct from global with distance-1 prefetch.

typedef _Float16 f16;
typedef _Float16 f16x8 __attribute__((ext_vector_type(8)));
typedef float    f32x4 __attribute__((ext_vector_type(4)));

#define BN_EPS_F 1e-3f

// ---------------------------------------------------------------------------
__global__ __launch_bounds__(256)
void fill_zero(float4* __restrict__ p, long n4)
{
    long i  = blockIdx.x * 256L + threadIdx.x;
    long st = (long)gridDim.x * 256L;
    float4 z = make_float4(0.f, 0.f, 0.f, 0.f);
    for (; i < n4; i += st) p[i] = z;
}

// input cast: vf f32 [3*M0][16] -> vf16 f16 [3*M0][32] (hi 16 ch zero)
__global__ __launch_bounds__(256)
void vf_convert(const float* __restrict__ vf, f16* __restrict__ vf16, int nrows)
{
    int i = blockIdx.x * 256 + threadIdx.x;
    if (i >= nrows * 32) return;
    int r = i >> 5, c = i & 31;
    vf16[i] = (c < 16) ? (f16)vf[r * 16 + c] : (f16)0;
}

// weight transforms: w [K][Ci][Co] f32 -> wT [K][Co][CiD] f16 (Ci zero-pad)
struct WXA { const float* s; f16* d; int K, Ci, Co, CiD, off; };
struct WXAll { WXA w[11]; };

__global__ __launch_bounds__(256)
void wxform_all(WXAll wa, int total)
{
    int i = blockIdx.x * 256 + threadIdx.x;
    if (i >= total) return;
    int j = 0;
    #pragma unroll
    for (int t = 1; t < 11; ++t) if (i >= wa.w[t].off) j = t;
    const float* s = wa.w[j].s;
    f16* d = wa.w[j].d;
    int Ci = wa.w[j].Ci, Co = wa.w[j].Co, CiD = wa.w[j].CiD;
    int e = i - wa.w[j].off;
    int cc = Co * CiD;
    int k = e / cc; int rem = e - k * cc;
    int co = rem / CiD; int ci = rem - co * CiD;
    float v = (ci < Ci) ? s[((size_t)k * Ci + ci) * Co + co] : 0.f;
    d[e] = (f16)v;
}

// ---------------------------------------------------------------------------
// gather-conv. Fragment layout (verified r2-r5): A/B lane l: row/col=l&15,
// k-contig 8 at (l>>4)*8; C/D: col=lane&15, row=(lane>>4)*4+reg.
// ---------------------------------------------------------------------------
template<int Ci, int Co, int K, bool SCATTER>
__global__ __launch_bounds__(256)
void gconv(const f16* __restrict__ fin, const int* __restrict__ idx,
           const f16* __restrict__ wT,    // [K][Co][Ci]
           const float* __restrict__ bnp, // [4][Co]
           const float* __restrict__ avec,
           f16* __restrict__ fout,
           const int* __restrict__ coords, float* __restrict__ dout,
           int M, int blocksPerFrame, long finStride, long foutStride)
{
    constexpr int NF  = Co / 16;       // column fragments
    constexpr int KK  = Ci / 32;       // MFMA k-steps per tap
    constexpr int CiP = Ci + 8;        // padded LDS row stride (2-way banks)
    constexpr int cpr = Ci / 8;        // 16B chunks per weight row
    constexpr int CH  = Co * cpr;      // 16B chunks per tap
    constexpr int NLD = (CH + 255) / 256;

    __shared__ f16 Bw[2][Co * CiP];
    __shared__ int sIdx[64][K];

    const int tid  = threadIdx.x;
    const int lane = tid & 63;
    const int wq   = tid >> 6;         // wave -> 16-row group
    const int l15  = lane & 15;
    const int kg   = lane >> 4;

    const int bid   = blockIdx.x;
    const int frame = bid / blocksPerFrame;
    const int fb    = bid - frame * blocksPerFrame;
    const f16* finF = fin + (long)frame * finStride;
    f16* foutF      = fout + (long)frame * foutStride;
    const int m0    = fb * 64;

    // stage idx tile + tap-0 weights, one barrier
    for (int i = tid; i < 64 * K; i += 256) {
        int r = i / K, k = i - r * K;
        int m = m0 + r;
        sIdx[r][k] = (m < M) ? idx[(long)m * K + k] : -1;
    }
    for (int i = tid; i < CH; i += 256) {
        int co = i / cpr, q = i - co * cpr;
        *(uint4*)&Bw[0][co * CiP + q * 8] = *(const uint4*)&wT[(long)co * Ci + q * 8];
    }
    __syncthreads();

    const int arow = wq * 16 + l15;    // this lane's output row in the tile

    // A(0) fragments
    f16x8 afc[KK];
    {
        int n = sIdx[arow][0];
        #pragma unroll
        for (int kk = 0; kk < KK; ++kk) {
            f16x8 v = {};
            if (n >= 0) v = *(const f16x8*)&finF[(long)n * Ci + kk * 32 + kg * 8];
            afc[kk] = v;
        }
    }

    f32x4 acc[NF];
    #pragma unroll
    for (int nf = 0; nf < NF; ++nf) acc[nf] = (f32x4){0.f, 0.f, 0.f, 0.f};

    #pragma unroll 1
    for (int k = 0; k < K; ++k) {
        const bool more = (k + 1 < K);
        // issue next-tap weight stage loads (global -> regs)
        uint4 wreg[NLD];
        if (more) {
            #pragma unroll
            for (int u = 0; u < NLD; ++u) {
                int i = tid + u * 256;
                if (i < CH) {
                    int co = i / cpr, q = i - co * cpr;
                    wreg[u] = *(const uint4*)&wT[((long)(k + 1) * Co + co) * Ci + q * 8];
                }
            }
        }
        // issue A(k+1) prefetch
        f16x8 afn[KK];
        {
            int n = more ? sIdx[arow][k + 1] : -1;
            #pragma unroll
            for (int kk = 0; kk < KK; ++kk) {
                f16x8 v = {};
                if (n >= 0) v = *(const f16x8*)&finF[(long)n * Ci + kk * 32 + kg * 8];
                afn[kk] = v;
            }
        }
        // compute tap k from LDS weights
        const f16* bwb = &Bw[k & 1][0];
        #pragma unroll
        for (int kk = 0; kk < KK; ++kk) {
            #pragma unroll
            for (int nf = 0; nf < NF; ++nf) {
                f16x8 bf = *(const f16x8*)&bwb[(nf * 16 + l15) * CiP + kk * 32 + kg * 8];
                acc[nf] = __builtin_amdgcn_mfma_f32_16x16x32_f16(afc[kk], bf, acc[nf], 0, 0, 0);
            }
        }
        // write staged weights, flip buffers
        if (more) {
            #pragma unroll
            for (int u = 0; u < NLD; ++u) {
                int i = tid + u * 256;
                if (i < CH) {
                    int co = i / cpr, q = i - co * cpr;
                    *(uint4*)&Bw[(k + 1) & 1][co * CiP + q * 8] = wreg[u];
                }
            }
            __syncthreads();
        }
        #pragma unroll
        for (int kk = 0; kk < KK; ++kk) afc[kk] = afn[kk];
    }

    // epilogue: BN + ReLU + store (each wave owns complete rows)
    #pragma unroll
    for (int nf = 0; nf < NF; ++nf) {
        int c = nf * 16 + l15;
        float gg = bnp[c], bb = bnp[Co + c], mu = bnp[2 * Co + c], vv = bnp[3 * Co + c];
        float sc = gg * rsqrtf(vv + BN_EPS_F);
        float sh = bb - mu * sc;
        float av = avec ? avec[c] : 0.f;
        #pragma unroll
        for (int j = 0; j < 4; ++j) {
            int m = m0 + wq * 16 + kg * 4 + j;
            if (m < M) {
                float x = acc[nf][j] + av;
                float y = fmaxf(fmaf(x, sc, sh), 0.f);
                foutF[(long)m * Co + c] = (f16)y;
                if (SCATTER) {
                    int z  = coords[m * 3 + 0];
                    int yy = coords[m * 3 + 1];
                    int xx = coords[m * 3 + 2];
                    dout[(long)(c * 4 + z) * (320 * 320) + yy * 320 + xx] = y;
                }
            }
        }
    }
}

// ---------------------------------------------------------------------------
// adapt: per-block partial of sum_rows relu(bn_ad(s @ w_ad1)) for all 3 levels
// ---------------------------------------------------------------------------
__global__ __launch_bounds__(64)
void adapt_partial3(const f16* __restrict__ x3, const f16* __restrict__ x7,
                    const f16* __restrict__ x11,
                    const float* __restrict__ w_ad1, const float* __restrict__ bn_ad,
                    float* __restrict__ pb,
                    int M1, int M2, int M3, int g1, int g2)
{
    __shared__ float wl[64 * 64];
    const int c = threadIdx.x;
    for (int i = c; i < 64 * 64; i += 64) wl[i] = w_ad1[i];
    float gg = bn_ad[c], bb = bn_ad[64 + c], mu = bn_ad[128 + c], vv = bn_ad[192 + c];
    float sc = gg * rsqrtf(vv + BN_EPS_F);
    float sh = bb - mu * sc;
    __syncthreads();

    int b = blockIdx.x;
    const f16* s; int M, r0;
    if (b < g1)           { s = x3;  M = M1; r0 = b * 64; }
    else if (b < g1 + g2) { s = x7;  M = M2; r0 = (b - g1) * 64; }
    else                  { s = x11; M = M3; r0 = (b - g1 - g2) * 64; }

    float hacc = 0.f;
    int r1 = min(r0 + 64, M);
    for (int r = r0; r < r1; ++r) {
        float acc = 0.f;
        #pragma unroll
        for (int i8 = 0; i8 < 8; ++i8) {
            f16x8 sv = *(const f16x8*)&s[(size_t)r * 64 + i8 * 8];
            #pragma unroll
            for (int e = 0; e < 8; ++e)
                acc = fmaf((float)sv[e], wl[(i8 * 8 + e) * 64 + c], acc);
        }
        hacc += fmaxf(fmaf(acc, sc, sh), 0.f);
    }
    pb[(size_t)b * 64 + c] = hacc;
}

__global__ __launch_bounds__(192)
void adapt_final3(const float* __restrict__ pb, const float* __restrict__ w_ad2,
                  float* __restrict__ av, int g1, int g2, int g3,
                  float invM1, float invM2, float invM3)
{
    __shared__ float h[3][64];
    const int lvl = threadIdx.x >> 6;
    const int c   = threadIdx.x & 63;
    int base = (lvl == 0) ? 0 : (lvl == 1 ? g1 : g1 + g2);
    int n    = (lvl == 0) ? g1 : (lvl == 1 ? g2 : g3);
    float invM = (lvl == 0) ? invM1 : (lvl == 1 ? invM2 : invM3);
    float acc = 0.f;
    for (int i = 0; i < n; ++i) acc += pb[(size_t)(base + i) * 64 + c];
    h[lvl][c] = acc * invM;
    __syncthreads();
    float o = 0.f;
    #pragma unroll 8
    for (int j = 0; j < 64; ++j) o = fmaf(h[lvl][j], w_ad2[j * 64 + c], o);
    av[lvl * 64 + c] = o * 0.1f;
}

// ---------------------------------------------------------------------------
extern "C" void kernel_launch(void* const* d_in, const int* in_sizes, int n_in,
                              void* d_out, int out_size, void* d_ws, size_t ws_size,
                              hipStream_t stream)
{
    const float* vf      = (const float*)d_in[0];
    const float* w_subm1 = (const float*)d_in[1];
    const float* w_subm2 = (const float*)d_in[2];
    const float* w_spcv1 = (const float*)d_in[3];
    const float* w_subm3 = (const float*)d_in[4];
    const float* w_subm4 = (const float*)d_in[5];
    const float* w_subm5 = (const float*)d_in[6];
    const float* w_spcv2 = (const float*)d_in[7];
    const float* w_subm6 = (const float*)d_in[8];
    const float* w_subm7 = (const float*)d_in[9];
    const float* w_subm8 = (const float*)d_in[10];
    const float* w_spcv3 = (const float*)d_in[11];
    const float* w_ad1   = (const float*)d_in[12];
    const float* w_ad2   = (const float*)d_in[13];
    const float* bn32    = (const float*)d_in[14];
    const float* bn64    = (const float*)d_in[15];
    const float* bn_ad   = (const float*)d_in[16];
    const int* nbr0    = (const int*)d_in[17];
    const int* idx1    = (const int*)d_in[18];
    const int* nbr1    = (const int*)d_in[19];
    const int* idx2    = (const int*)d_in[20];
    const int* nbr2    = (const int*)d_in[21];
    const int* idx3    = (const int*)d_in[22];
    const int* coords3 = (const int*)d_in[23];

    const int M0 = in_sizes[0]  / (3 * 16);
    const int M1 = in_sizes[18] / 27;
    const int M2 = in_sizes[20] / 27;
    const int M3 = in_sizes[22] / 3;

    char* base = (char*)d_ws;
    size_t off = 0;
    auto alloc = [&](size_t bytes) -> void* {
        void* p = base + off;
        off = (off + bytes + 255) & ~(size_t)255;
        return p;
    };
    // weights [K][Co][CiD] f16
    f16* wt1  = (f16*)alloc((size_t)27 * 32 * 32 * 2);
    f16* wt2  = (f16*)alloc((size_t)27 * 32 * 32 * 2);
    f16* wtc1 = (f16*)alloc((size_t)27 * 64 * 32 * 2);
    f16* wt3  = (f16*)alloc((size_t)27 * 64 * 64 * 2);
    f16* wt4  = (f16*)alloc((size_t)27 * 64 * 64 * 2);
    f16* wt5  = (f16*)alloc((size_t)27 * 64 * 64 * 2);
    f16* wtc2 = (f16*)alloc((size_t)27 * 64 * 64 * 2);
    f16* wt6  = (f16*)alloc((size_t)27 * 64 * 64 * 2);
    f16* wt7  = (f16*)alloc((size_t)27 * 64 * 64 * 2);
    f16* wt8  = (f16*)alloc((size_t)27 * 64 * 64 * 2);
    f16* wtc3 = (f16*)alloc((size_t)3  * 64 * 64 * 2);
    // features
    f16* vf16  = (f16*)alloc((size_t)3 * M0 * 32 * 2);
    f16* buf0a = (f16*)alloc((size_t)3 * M0 * 32 * 2);
    f16* buf0b = (f16*)alloc((size_t)3 * M0 * 32 * 2);
    f16* x3    = (f16*)alloc((size_t)M1 * 64 * 2);
    f16* buf1a = (f16*)alloc((size_t)M1 * 64 * 2);
    f16* buf1b = (f16*)alloc((size_t)M1 * 64 * 2);
    f16* x7    = (f16*)alloc((size_t)M2 * 64 * 2);
    f16* buf2a = (f16*)alloc((size_t)M2 * 64 * 2);
    f16* buf2b = (f16*)alloc((size_t)M2 * 64 * 2);
    f16* x11   = (f16*)alloc((size_t)M3 * 64 * 2);
    float* av  = (float*)alloc(192 * 4);
    const int g1a = (M1 + 63) / 64, g2a = (M2 + 63) / 64, g3a = (M3 + 63) / 64;
    float* pb  = (float*)alloc((size_t)(g1a + g2a + g3a) * 64 * 4);
    (void)ws_size; (void)n_in;

    // --- setup: weight transforms (1 launch), input cast (1), output zero (1)
    WXAll wa;
    int woff = 0;
    auto addw = [&](int slot, const float* s, f16* d, int K, int Ci, int Co, int CiD) {
        wa.w[slot] = {s, d, K, Ci, Co, CiD, woff};
        woff += K * Co * CiD;
    };
    addw(0,  w_subm1, wt1,  27, 16, 32, 32);
    addw(1,  w_subm2, wt2,  27, 32, 32, 32);
    addw(2,  w_spcv1, wtc1, 27, 32, 64, 32);
    addw(3,  w_subm3, wt3,  27, 64, 64, 64);
    addw(4,  w_subm4, wt4,  27, 64, 64, 64);
    addw(5,  w_subm5, wt5,  27, 64, 64, 64);
    addw(6,  w_spcv2, wtc2, 27, 64, 64, 64);
    addw(7,  w_subm6, wt6,  27, 64, 64, 64);
    addw(8,  w_subm7, wt7,  27, 64, 64, 64);
    addw(9,  w_subm8, wt8,  27, 64, 64, 64);
    addw(10, w_spcv3, wtc3, 3,  64, 64, 64);
    wxform_all<<<(woff + 255) / 256, 256, 0, stream>>>(wa, woff);
    vf_convert<<<(3 * M0 * 32 + 255) / 256, 256, 0, stream>>>(vf, vf16, 3 * M0);
    fill_zero<<<2048, 256, 0, stream>>>((float4*)d_out, (long)out_size / 4);

    const int g0 = (M0 + 63) / 64;
    const int g1 = (M1 + 63) / 64;
    const int g2 = (M2 + 63) / 64;
    const int g3 = (M3 + 63) / 64;
    const long s0 = (long)M0 * 32;

    // batched over all 3 frames (independent of temporal state)
    gconv<32,32,27,false><<<3 * g0, 256, 0, stream>>>(
        vf16,  nbr0, wt1, bn32,       nullptr, buf0a, nullptr, nullptr, M0, g0, s0, s0);
    gconv<32,32,27,false><<<3 * g0, 256, 0, stream>>>(
        buf0a, nbr0, wt2, bn32 + 128, nullptr, buf0b, nullptr, nullptr, M0, g0, s0, s0);

    for (int t = 0; t < 3; ++t) {
        const float* a0 = (t == 0) ? nullptr : av + 0;
        const float* a1 = (t == 0) ? nullptr : av + 64;
        const float* a2 = (t == 0) ? nullptr : av + 128;
        float* doutT = (float*)d_out + (size_t)t * 256 * 320 * 320;

        gconv<32,64,27,false><<<g1, 256, 0, stream>>>(
            buf0b + (long)t * s0, idx1, wtc1, bn64, a0, x3, nullptr, nullptr, M1, g1, 0, 0);
        gconv<64,64,27,false><<<g1, 256, 0, stream>>>(
            x3,    nbr1, wt3, bn64 + 256,  nullptr, buf1a, nullptr, nullptr, M1, g1, 0, 0);
        gconv<64,64,27,false><<<g1, 256, 0, stream>>>(
            buf1a, nbr1, wt4, bn64 + 512,  nullptr, buf1b, nullptr, nullptr, M1, g1, 0, 0);
        gconv<64,64,27,false><<<g1, 256, 0, stream>>>(
            buf1b, nbr1, wt5, bn64 + 768,  nullptr, buf1a, nullptr, nullptr, M1, g1, 0, 0);
        gconv<64,64,27,false><<<g2, 256, 0, stream>>>(
            buf1a, idx2, wtc2, bn64 + 1024, a1,     x7,    nullptr, nullptr, M2, g2, 0, 0);
        gconv<64,64,27,false><<<g2, 256, 0, stream>>>(
            x7,    nbr2, wt6, bn64 + 1280, nullptr, buf2a, nullptr, nullptr, M2, g2, 0, 0);
        gconv<64,64,27,false><<<g2, 256, 0, stream>>>(
            buf2a, nbr2, wt7, bn64 + 1536, nullptr, buf2b, nullptr, nullptr, M2, g2, 0, 0);
        gconv<64,64,27,false><<<g2, 256, 0, stream>>>(
            buf2b, nbr2, wt8, bn64 + 1792, nullptr, buf2a, nullptr, nullptr, M2, g2, 0, 0);
        gconv<64,64,3,true><<<g3, 256, 0, stream>>>(
            buf2a, idx3, wtc3, bn64 + 2048, a2,    x11,   coords3, doutT,   M3, g3, 0, 0);

        if (t < 2) {
            adapt_partial3<<<g1a + g2a + g3a, 64, 0, stream>>>(
                x3, x7, x11, w_ad1, bn_ad, pb, M1, M2, M3, g1a, g2a);
            adapt_final3<<<1, 192, 0, stream>>>(
                pb, w_ad2, av, g1a, g2a, g3a, 1.f / M1, 1.f / M2, 1.f / M3);
        }
    }
}